// Round 1
// baseline (2292.791 us; speedup 1.0000x reference)
//
#include <hip/hip_runtime.h>
#include <math.h>

// ConvTranspose2d(64,64,k=4,s=2,p=1) + bias + Mish + 0.5, clamp [-1,1], *2
// x: (64,64,64,64) f32, w: (64,64,4,4) f32 (OIHW of the *forward* conv in the
// reference, i.e. already the "flip" source), bias: (64,) f32
// out: (64,64,128,128) f32
//
// Gather form: out[n,oc,oh,ow] = sum_{ic,j,k} x[n,ic,ih_j,iw_k] * w[oc,ic,wkh_j,wkw_k]
//   r=oh&1: ih_j = ((oh-2+r)>>1)+j, wkh_j = 3-r-2j   (j=0,1)
//   s=ow&1: iw_k = ((ow-2+s)>>1)+k, wkw_k = 3-s-2k   (k=0,1)
// Lane t handles ow=2t (cols t-1,t) and ow=2t+1 (cols t,t+1); cols via shfl.

#define X_HW 4096   // 64*64
#define OW_STRIDE 128

__device__ __forceinline__ float act_fused(float y) {
    // mish(y) = y * tanh(log1p(exp(y)))
    float sp = (y > 20.f) ? y : log1pf(expf(y));
    float m = y * tanhf(sp);
    float v = m + 0.5f;
    v = fminf(fmaxf(v, -1.f), 1.f);
    return v * 2.f;
}

__global__ __launch_bounds__(256) void convt_mish_kernel(
    const float* __restrict__ x, const float* __restrict__ w,
    const float* __restrict__ bias, float* __restrict__ out)
{
    const int t   = threadIdx.x;                 // 0..63, lane (ow pair index)
    const int wv  = threadIdx.y;                 // 0..3, wave in block
    const int oh  = blockIdx.x;                  // 0..127
    const int ocb = blockIdx.y * 32 + wv * 8;    // 8 oc per wave
    const int n   = blockIdx.z;                  // 0..63

    const int r   = oh & 1;
    const int ih0 = (oh - 2 + r) >> 1;
    const int ih1 = ih0 + 1;
    const bool mT = (ih0 >= 0);
    const bool mB = (ih1 < 64);
    const int cih0 = mT ? ih0 : 0;
    const int cih1 = mB ? ih1 : 63;
    const bool mL = (t >= 1);
    const bool mR = (t <= 62);

    const float* xb  = x + (size_t)n * 64 * X_HW;
    const float* xr0 = xb + cih0 * 64 + t;
    const float* xr1 = xb + cih1 * 64 + t;
    const int kh0 = 3 - r;   // weight row for ih0
    const int kh1 = 1 - r;   // weight row for ih1

    float acc_e[8], acc_o[8];
#pragma unroll
    for (int o = 0; o < 8; ++o) { acc_e[o] = 0.f; acc_o[o] = 0.f; }

    const float* wb = w + (size_t)ocb * 1024;    // oc stride = 64*16 = 1024

    for (int ic = 0; ic < 64; ++ic) {
        float a = xr0[ic * X_HW];
        float b = xr1[ic * X_HW];
        a = mT ? a : 0.f;
        b = mB ? b : 0.f;
        float aL = __shfl_up(a, 1);
        float bL = __shfl_up(b, 1);
        float aR = __shfl_down(a, 1);
        float bR = __shfl_down(b, 1);
        aL = mL ? aL : 0.f;  bL = mL ? bL : 0.f;
        aR = mR ? aR : 0.f;  bR = mR ? bR : 0.f;

        const float* wp = wb + ic * 16;
#pragma unroll
        for (int o = 0; o < 8; ++o) {
            const float4 wA = *(const float4*)(wp + o * 1024 + kh0 * 4);
            const float4 wB = *(const float4*)(wp + o * 1024 + kh1 * 4);
            // even ow: cols (t-1 -> kw3), (t -> kw1)
            acc_e[o] += aL * wA.w + a * wA.y + bL * wB.w + b * wB.y;
            // odd ow: cols (t -> kw2), (t+1 -> kw0)
            acc_o[o] += a * wA.z + aR * wA.x + b * wB.z + bR * wB.x;
        }
    }

    const size_t obase = (((size_t)n * 64 + ocb) * 128 + oh) * OW_STRIDE + 2 * t;
#pragma unroll
    for (int o = 0; o < 8; ++o) {
        const float bs = bias[ocb + o];
        float2 res;
        res.x = act_fused(acc_e[o] + bs);
        res.y = act_fused(acc_o[o] + bs);
        *(float2*)(out + obase + (size_t)o * 128 * OW_STRIDE) = res;
    }
}

extern "C" void kernel_launch(void* const* d_in, const int* in_sizes, int n_in,
                              void* d_out, int out_size, void* d_ws, size_t ws_size,
                              hipStream_t stream) {
    const float* x    = (const float*)d_in[0];
    const float* wgt  = (const float*)d_in[1];
    const float* bias = (const float*)d_in[2];
    float* out = (float*)d_out;

    dim3 grid(128, 2, 64);   // oh, oc-group(32 oc), n
    dim3 block(64, 4, 1);    // lane (ow pair), wave (8 oc each)
    convt_mish_kernel<<<grid, block, 0, stream>>>(x, wgt, bias, out);
}

// Round 2
// 452.080 us; speedup vs baseline: 5.0717x; 5.0717x over previous
//
#include <hip/hip_runtime.h>
#include <math.h>

// ConvTranspose2d(64,64,k4,s2,p1) + bias + mish + 0.5 clamp[-1,1] *2, via MFMA.
// Quadrant decomposition: output parity (r,s) -> 2x2 stride-1 conv:
//   out[n,oc,2y+r,2x+s] = sum_{ic,j,kk} x[n,ic,y-1+r+j,x-1+s+kk] * w[oc,ic,3-r-2j,3-s-2kk]
// GEMM per (n,y,quadrant): M=64 oc, N=64 x-positions, K=256=(j,kk)x64ic.
// Block: one n, 8 consecutive y. 4 waves = 4 quadrants. Weights as persistent
// A-fragments in VGPRs; x rows staged to LDS bf16 [row][colp][ic] (swizzled) so
// each B-fragment is one ds_read_b128.

typedef __attribute__((ext_vector_type(8))) short bf16x8;
typedef __attribute__((ext_vector_type(4))) float floatx4;

__device__ __forceinline__ unsigned short f2bf(float f) {
    unsigned int u = __float_as_uint(f);
    u += 0x7fffu + ((u >> 16) & 1u);
    return (unsigned short)(u >> 16);
}

__device__ __forceinline__ unsigned long long pack4(unsigned short a, unsigned short b,
                                                    unsigned short c, unsigned short d) {
    return (unsigned long long)a | ((unsigned long long)b << 16) |
           ((unsigned long long)c << 32) | ((unsigned long long)d << 48);
}

__device__ __forceinline__ float act(float y) {
    float ax = fabsf(y);
    float sp = fmaxf(y, 0.f) + __logf(1.f + __expf(-ax));   // softplus, stable
    float e2 = __expf(2.f * sp);
    float th = 1.f - 2.f / (e2 + 1.f);                      // tanh(sp), sp>=0
    float v = y * th + 0.5f;
    v = fminf(fmaxf(v, -1.f), 1.f);
    return v * 2.f;
}

__global__ __launch_bounds__(256, 2) void convt_mfma(
    const float* __restrict__ x, const float* __restrict__ w,
    const float* __restrict__ bias, float* __restrict__ out)
{
    __shared__ unsigned short lds[16384];   // 32 KB: weight scratch, then x rows [3][66][64]

    const int tid  = threadIdx.x;
    const int lane = tid & 63;
    const int wid  = tid >> 6;
    const int r = wid >> 1, s = wid & 1;        // quadrant
    const int q = lane >> 4, mcol = lane & 15;  // MFMA lane decomposition

    const int bid = blockIdx.x;
    const int n   = bid >> 3;
    const int y0  = (bid & 7) * 8;

    const float* xn = x + (size_t)n * 262144;   // 64*64*64

    // ---------------- stage weights -> persistent A fragments ----------------
    // k ordering: k = (j*2+kk)*64 + ic. A[oc][k] -> frag a[mt][ks], oc=16mt+mcol,
    // lane holds k = 32ks + 8q + [0..8) = 8 consecutive ic of tap (j,kk)=ks>>1.
    bf16x8 a[4][8];
    {
        const int tap = tid & 15;        // kh*4+kw flat
        const int icq = tid >> 4;        // 0..15
        const int icw = icq * 4;
        for (int c = 0; c < 4; ++c) {    // oc chunk = 16
            __syncthreads();
            #pragma unroll
            for (int it = 0; it < 16; ++it) {
                const float* wp = w + ((16 * c + it) * 1024 + icw * 16 + tap);
                unsigned long long pk = pack4(f2bf(wp[0]), f2bf(wp[16]),
                                              f2bf(wp[32]), f2bf(wp[48]));
                *(unsigned long long*)&lds[(it * 16 + tap) * 64 + (icw ^ ((tap & 7) * 8))] = pk;
            }
            __syncthreads();
            #pragma unroll
            for (int ks = 0; ks < 8; ++ks) {
                const int tl = ks >> 1;
                const int j = tl >> 1, kk = tl & 1;
                const int kh = 3 - r - 2 * j, kw = 3 - s - 2 * kk;
                const int tapidx = kh * 4 + kw;
                const int ic0 = (ks & 1) * 32 + q * 8;
                a[c][ks] = *(const bf16x8*)&lds[(mcol * 16 + tapidx) * 64 +
                                                (ic0 ^ ((tapidx & 7) * 8))];
            }
        }
    }

    // bias per lane: oc = 16mt + 4q + rg
    float bv[4][4];
    #pragma unroll
    for (int mt = 0; mt < 4; ++mt)
        #pragma unroll
        for (int rg = 0; rg < 4; ++rg)
            bv[mt][rg] = bias[mt * 16 + q * 4 + rg];

    floatx4 acc[4][4];

    for (int iy = 0; iy < 8; ++iy) {
        const int y = y0 + iy;
        __syncthreads();   // previous compute's LDS reads complete

        // ---- phase A: stage x rows (y-1,y,y+1) -> lds[row][colp][ic] bf16 ----
        {
            const int col0 = (tid & 31) * 2;
            const int g    = tid >> 5;       // 0..7 -> 8 ic each
            #pragma unroll
            for (int row = 0; row < 3; ++row) {
                const int ry = y - 1 + row;
                const bool val = (ry >= 0) && (ry < 64);
                const int rc = val ? ry : 0;
                const float* xp = xn + rc * 64 + col0;
                #pragma unroll
                for (int sub = 0; sub < 2; ++sub) {
                    const int ic0 = g * 8 + sub * 4;
                    float2 v0 = *(const float2*)(xp + (size_t)(ic0 + 0) * 4096);
                    float2 v1 = *(const float2*)(xp + (size_t)(ic0 + 1) * 4096);
                    float2 v2 = *(const float2*)(xp + (size_t)(ic0 + 2) * 4096);
                    float2 v3 = *(const float2*)(xp + (size_t)(ic0 + 3) * 4096);
                    if (!val) { v0.x=v0.y=v1.x=v1.y=v2.x=v2.y=v3.x=v3.y=0.f; }
                    const int cp0 = col0 + 1, cp1 = col0 + 2;
                    *(unsigned long long*)&lds[(row * 66 + cp0) * 64 + (ic0 ^ ((cp0 & 7) * 8))] =
                        pack4(f2bf(v0.x), f2bf(v1.x), f2bf(v2.x), f2bf(v3.x));
                    *(unsigned long long*)&lds[(row * 66 + cp1) * 64 + (ic0 ^ ((cp1 & 7) * 8))] =
                        pack4(f2bf(v0.y), f2bf(v1.y), f2bf(v2.y), f2bf(v3.y));
                }
            }
            if (tid < 96) {  // halo cols -1 and 64 -> zeros
                const int rowz = tid >> 5;
                const int cp   = ((tid >> 4) & 1) ? 65 : 0;
                const int icz  = (tid & 15) * 4;
                *(unsigned long long*)&lds[(rowz * 66 + cp) * 64 + (icz ^ ((cp & 7) * 8))] = 0ULL;
            }
        }

        // ---- epilogue of previous y (overlaps staging latency) ----
        if (iy > 0) {
            const int oh = 2 * (y - 1) + r;
            #pragma unroll
            for (int mt = 0; mt < 4; ++mt)
                #pragma unroll
                for (int nt = 0; nt < 4; ++nt) {
                    const int ow = 2 * (nt * 16 + mcol) + s;
                    #pragma unroll
                    for (int rg = 0; rg < 4; ++rg) {
                        const int oc = mt * 16 + q * 4 + rg;
                        out[(((size_t)n * 64 + oc) * 128 + oh) * 128 + ow] =
                            act(acc[mt][nt][rg] + bv[mt][rg]);
                    }
                }
        }

        __syncthreads();

        // ---- phase B: MFMA compute ----
        #pragma unroll
        for (int mt = 0; mt < 4; ++mt)
            #pragma unroll
            for (int nt = 0; nt < 4; ++nt)
                acc[mt][nt] = (floatx4){0.f, 0.f, 0.f, 0.f};

        #pragma unroll
        for (int ks = 0; ks < 8; ++ks) {
            const int tl = ks >> 1;
            const int j = tl >> 1, kk = tl & 1;
            const int rowidx = r + j;                // 0..2
            const int ic0 = (ks & 1) * 32 + q * 8;
            bf16x8 b[4];
            #pragma unroll
            for (int nt = 0; nt < 4; ++nt) {
                const int cp = nt * 16 + mcol + kk + s;   // 0..65
                b[nt] = *(const bf16x8*)&lds[(rowidx * 66 + cp) * 64 + (ic0 ^ ((cp & 7) * 8))];
            }
            #pragma unroll
            for (int mt = 0; mt < 4; ++mt)
                #pragma unroll
                for (int nt = 0; nt < 4; ++nt)
                    acc[mt][nt] = __builtin_amdgcn_mfma_f32_16x16x32_bf16(
                        a[mt][ks], b[nt], acc[mt][nt], 0, 0, 0);
        }
    }

    // ---- final epilogue (y = y0+7) ----
    {
        const int oh = 2 * (y0 + 7) + r;
        #pragma unroll
        for (int mt = 0; mt < 4; ++mt)
            #pragma unroll
            for (int nt = 0; nt < 4; ++nt) {
                const int ow = 2 * (nt * 16 + mcol) + s;
                #pragma unroll
                for (int rg = 0; rg < 4; ++rg) {
                    const int oc = mt * 16 + q * 4 + rg;
                    out[(((size_t)n * 64 + oc) * 128 + oh) * 128 + ow] =
                        act(acc[mt][nt][rg] + bv[mt][rg]);
                }
            }
    }
}

extern "C" void kernel_launch(void* const* d_in, const int* in_sizes, int n_in,
                              void* d_out, int out_size, void* d_ws, size_t ws_size,
                              hipStream_t stream) {
    const float* x    = (const float*)d_in[0];
    const float* wgt  = (const float*)d_in[1];
    const float* bias = (const float*)d_in[2];
    float* out = (float*)d_out;

    convt_mfma<<<dim3(512), dim3(256), 0, stream>>>(x, wgt, bias, out);
}

// Round 3
// 377.922 us; speedup vs baseline: 6.0668x; 1.1962x over previous
//
#include <hip/hip_runtime.h>
#include <math.h>

// ConvTranspose2d(64,64,k4,s2,p1) + bias + mish + 0.5 clamp[-1,1] *2, via MFMA.
// Quadrant decomposition: output parity (r,s) -> 2x2 stride-1 conv.
// GEMM per (n,y,quadrant): M=64 oc, N=64 x-pos, K=256=(j,kk)x64ic.
// v3: rolling 4-slot LDS row ring (1 new row/iter), register prefetch of the
// next row across the compute phase, cheap exp-based mish epilogue.

typedef __attribute__((ext_vector_type(8))) short bf16x8;
typedef __attribute__((ext_vector_type(4))) float floatx4;

#define LDS_ROW 4224   // 66 cols * 64 ic (ushort units)

__device__ __forceinline__ unsigned short f2bf(float f) {
    unsigned int u = __float_as_uint(f);
    u += 0x7fffu + ((u >> 16) & 1u);
    return (unsigned short)(u >> 16);
}

__device__ __forceinline__ unsigned long long pack4(unsigned short a, unsigned short b,
                                                    unsigned short c, unsigned short d) {
    return (unsigned long long)a | ((unsigned long long)b << 16) |
           ((unsigned long long)c << 32) | ((unsigned long long)d << 48);
}

__device__ __forceinline__ float act(float y) {
    // mish(y) = y*tanh(softplus(y)); tanh(ln(1+e)) = (e^2+2e)/(e^2+2e+2)
    // lower clamp never binds (mish+0.5 >= 0.19); y>8 saturates upper clamp.
    float t = fminf(y, 8.f);
    float e = __expf(t);
    float p = e * (e + 2.f);
    float m = t * p * __builtin_amdgcn_rcpf(p + 2.f);
    float v = fminf(m + 0.5f, 1.f);
    return v + v;
}

__global__ __launch_bounds__(256, 2) void convt_mfma3(
    const float* __restrict__ x, const float* __restrict__ w,
    const float* __restrict__ bias, float* __restrict__ out)
{
    __shared__ unsigned short lds[16896];   // 33 KB: 4-slot row ring (+weight scratch)

    const int tid  = threadIdx.x;
    const int lane = tid & 63;
    const int wid  = tid >> 6;
    const int r = wid >> 1, s = wid & 1;        // quadrant
    const int q = lane >> 4, mcol = lane & 15;  // MFMA lane decomposition

    const int bid = blockIdx.x;
    const int n   = bid >> 3;
    const int y0  = (bid & 7) * 8;

    const float* xn = x + (size_t)n * 262144;   // 64*64*64

    // ---------------- stage weights -> persistent A fragments ----------------
    bf16x8 a[4][8];
    {
        const int tap = tid & 15;
        const int icq = tid >> 4;
        const int icw = icq * 4;
        for (int c = 0; c < 4; ++c) {
            __syncthreads();
            #pragma unroll
            for (int it = 0; it < 16; ++it) {
                const float* wp = w + ((16 * c + it) * 1024 + icw * 16 + tap);
                unsigned long long pk = pack4(f2bf(wp[0]), f2bf(wp[16]),
                                              f2bf(wp[32]), f2bf(wp[48]));
                *(unsigned long long*)&lds[(it * 16 + tap) * 64 + (icw ^ ((tap & 7) * 8))] = pk;
            }
            __syncthreads();
            #pragma unroll
            for (int ks = 0; ks < 8; ++ks) {
                const int tl = ks >> 1;
                const int j = tl >> 1, kk = tl & 1;
                const int kh = 3 - r - 2 * j, kw = 3 - s - 2 * kk;
                const int tapidx = kh * 4 + kw;
                const int ic0 = (ks & 1) * 32 + q * 8;
                a[c][ks] = *(const bf16x8*)&lds[(mcol * 16 + tapidx) * 64 +
                                                (ic0 ^ ((tapidx & 7) * 8))];
            }
        }
    }

    float bv[4][4];
    #pragma unroll
    for (int mt = 0; mt < 4; ++mt)
        #pragma unroll
        for (int rg = 0; rg < 4; ++rg)
            bv[mt][rg] = bias[mt * 16 + q * 4 + rg];

    __syncthreads();   // a-frag reads done; lds becomes the x row ring

    // staging thread mapping: 4 cols x 4 ic per thread
    const int colg = tid & 15, icg = tid >> 4;
    const int c0 = colg * 4, ic0s = icg * 4;

    auto write_row = [&](int slot, const float4& v0, const float4& v1,
                         const float4& v2, const float4& v3) {
        #pragma unroll
        for (int k = 0; k < 4; ++k) {
            const int cp = c0 + k + 1;
            unsigned long long pk = pack4(f2bf((&v0.x)[k]), f2bf((&v1.x)[k]),
                                          f2bf((&v2.x)[k]), f2bf((&v3.x)[k]));
            *(unsigned long long*)&lds[slot * LDS_ROW + cp * 64 +
                                       (ic0s ^ ((cp & 7) * 8))] = pk;
        }
    };
    auto load_row = [&](int ry, float4& v0, float4& v1, float4& v2, float4& v3) {
        const float* xp = xn + (size_t)ic0s * 4096 + ry * 64 + c0;
        v0 = *(const float4*)(xp);
        v1 = *(const float4*)(xp + 4096);
        v2 = *(const float4*)(xp + 8192);
        v3 = *(const float4*)(xp + 12288);
    };
    const float4 z4 = {0.f, 0.f, 0.f, 0.f};

    // halo cols (cp=0,65) are zero for every row: zero once, all 4 slots
    if (tid < 64) {
        const int slot = tid >> 4;
        const int cpz  = ((tid >> 3) & 1) ? 65 : 0;
        const int part = tid & 7;   // 8 ushorts each
        unsigned long long* p =
            (unsigned long long*)&lds[slot * LDS_ROW + cpz * 64 + part * 8];
        p[0] = 0ULL; p[1] = 0ULL;
    }

    // prologue: rows y0-1, y0, y0+1 -> slots 0,1,2
    #pragma unroll
    for (int pr = 0; pr < 3; ++pr) {
        const int ry = y0 - 1 + pr;
        float4 v0 = z4, v1 = z4, v2 = z4, v3 = z4;
        if (ry >= 0 && ry < 64) load_row(ry, v0, v1, v2, v3);
        write_row(pr, v0, v1, v2, v3);
    }

    for (int iy = 0; iy < 8; ++iy) {
        const int y = y0 + iy;
        __syncthreads();   // ring writes visible; prev iter's reads done

        // prefetch next row into registers (consumed at end of this iter)
        const int ry_pf = y + 2;
        const bool pf_valid = (iy < 7) && (ry_pf < 64);
        float4 p0 = z4, p1 = z4, p2 = z4, p3 = z4;
        if (pf_valid) load_row(ry_pf, p0, p1, p2, p3);

        // ---- MFMA compute for output row pair at y ----
        floatx4 acc[4][4];
        #pragma unroll
        for (int mt = 0; mt < 4; ++mt)
            #pragma unroll
            for (int nt = 0; nt < 4; ++nt)
                acc[mt][nt] = (floatx4){0.f, 0.f, 0.f, 0.f};

        #pragma unroll
        for (int ks = 0; ks < 8; ++ks) {
            const int tl = ks >> 1;
            const int j = tl >> 1, kk = tl & 1;
            const int slotj = (iy + r + j) & 3;         // row y-1+r+j
            const int icb = (ks & 1) * 32 + q * 8;
            bf16x8 b[4];
            #pragma unroll
            for (int nt = 0; nt < 4; ++nt) {
                const int cp = nt * 16 + mcol + kk + s;
                b[nt] = *(const bf16x8*)&lds[slotj * LDS_ROW + cp * 64 +
                                             (icb ^ ((cp & 7) * 8))];
            }
            #pragma unroll
            for (int mt = 0; mt < 4; ++mt)
                #pragma unroll
                for (int nt = 0; nt < 4; ++nt)
                    acc[mt][nt] = __builtin_amdgcn_mfma_f32_16x16x32_bf16(
                        a[mt][ks], b[nt], acc[mt][nt], 0, 0, 0);
        }

        // ---- epilogue ----
        {
            const int oh = 2 * y + r;
            #pragma unroll
            for (int mt = 0; mt < 4; ++mt)
                #pragma unroll
                for (int nt = 0; nt < 4; ++nt) {
                    const int ow = 2 * (nt * 16 + mcol) + s;
                    #pragma unroll
                    for (int rg = 0; rg < 4; ++rg) {
                        const int oc = mt * 16 + q * 4 + rg;
                        out[(((size_t)n * 64 + oc) * 128 + oh) * 128 + ow] =
                            act(acc[mt][nt][rg] + bv[mt][rg]);
                    }
                }
        }

        // ---- convert prefetch regs, write row y+2 into ring ----
        if (iy < 7) {
            write_row((iy + 3) & 3, p0, p1, p2, p3);
        }
    }
}

extern "C" void kernel_launch(void* const* d_in, const int* in_sizes, int n_in,
                              void* d_out, int out_size, void* d_ws, size_t ws_size,
                              hipStream_t stream) {
    const float* x    = (const float*)d_in[0];
    const float* wgt  = (const float*)d_in[1];
    const float* bias = (const float*)d_in[2];
    float* out = (float*)d_out;

    convt_mfma3<<<dim3(512), dim3(256), 0, stream>>>(x, wgt, bias, out);
}